// Round 1
// baseline (15711.903 us; speedup 1.0000x reference)
//
#include <hip/hip_runtime.h>
#include <hip/hip_bf16.h>
#include <math.h>

#define L_SEQ   2048
#define NEMBD   1024
#define DINNER  2048
#define DSTATE  16
#define DTRANK  64
#define DCONV   4
#define VOCAB   50257
#define NLAYERS 4

__device__ __forceinline__ float silu_f(float x) { return x / (1.f + __expf(-x)); }
__device__ __forceinline__ float softplus_f(float x) { return x > 20.f ? x : log1pf(__expf(x)); }

// ---------------- embedding gather: x[l,e] = emb_W[tok[l], e] ----------------
__global__ void embed_k(const int* __restrict__ tok, const float* __restrict__ W,
                        float* __restrict__ x) {
    int idx = blockIdx.x * 256 + threadIdx.x;           // over L_SEQ*NEMBD
    int l = idx >> 10, e = idx & 1023;
    x[idx] = W[(size_t)tok[l] * NEMBD + e];
}

// ---------------- rmsnorm over last dim (N=1024), one block per row ----------
__global__ void rmsnorm_k(const float* __restrict__ x, const float* __restrict__ w,
                          const float* __restrict__ b, float* __restrict__ o) {
    int l = blockIdx.x;
    const float* xr = x + (size_t)l * NEMBD;
    float ss = 0.f;
    for (int i = threadIdx.x; i < NEMBD; i += 256) { float v = xr[i]; ss += v * v; }
    __shared__ float red[4];
    for (int off = 32; off > 0; off >>= 1) ss += __shfl_down(ss, off, 64);
    if ((threadIdx.x & 63) == 0) red[threadIdx.x >> 6] = ss;
    __syncthreads();
    if (threadIdx.x == 0) {
        float t = red[0] + red[1] + red[2] + red[3];
        red[0] = rsqrtf(t / (float)NEMBD + 1e-6f);
    }
    __syncthreads();
    float inv = red[0];
    for (int i = threadIdx.x; i < NEMBD; i += 256)
        o[(size_t)l * NEMBD + i] = xr[i] * inv * w[i] + b[i];
}

// ---------------- depthwise causal conv (width 4) + bias + silu --------------
// input = xr[:, :DINNER] (row stride 2*DINNER); out xc [L, DINNER]
__global__ void conv_silu_k(const float* __restrict__ xr, const float* __restrict__ cw,
                            const float* __restrict__ cb, float* __restrict__ xc) {
    int idx = blockIdx.x * 256 + threadIdx.x;           // over L_SEQ*DINNER
    int d = idx & (DINNER - 1); int l = idx >> 11;
    const float* w = cw + (size_t)d * DCONV;
    float acc = cb[d];
#pragma unroll
    for (int j = 0; j < DCONV; j++) {
        int t = l - (DCONV - 1) + j;
        if (t >= 0) acc = fmaf(xr[(size_t)t * (2 * DINNER) + d], w[j], acc);
    }
    xc[idx] = silu_f(acc);
}

// ---------------- y[l,d] *= silu(res[l,d]),  res = xr[:, DINNER:] ------------
__global__ void mul_silu_k(float* __restrict__ y, const float* __restrict__ xr) {
    int idx = blockIdx.x * 256 + threadIdx.x;
    int d = idx & (DINNER - 1); int l = idx >> 11;
    float r = xr[(size_t)l * (2 * DINNER) + DINNER + d];
    y[idx] *= silu_f(r);
}

// ---------------- generic GEMM: C[M,N] = A[M,K] @ B[N,K]^T -------------------
// EPI: 0 = plain store; 1 = softplus(acc + bias[n]); 2 = C += acc
#define BM 128
#define BN 128
#define BK 16
template <int EPI>
__global__ __launch_bounds__(256) void gemm_bt(
    const float* __restrict__ A, int lda,
    const float* __restrict__ B, int ldb,
    float* __restrict__ C, int ldc,
    const float* __restrict__ bias,
    int M, int N, int K) {
    __shared__ float As[BK][BM + 4];
    __shared__ float Bs[BK][BN + 4];
    int tid = threadIdx.x;
    int bm = blockIdx.y * BM;
    int bn = blockIdx.x * BN;
    int tx = tid & 15, ty = tid >> 4;
    float acc[8][8] = {};
    for (int k0 = 0; k0 < K; k0 += BK) {
#pragma unroll
        for (int i = 0; i < 8; i++) {
            int idx = tid + i * 256;
            int r = idx >> 4, c = idx & 15;
            int gr = bm + r, gc = k0 + c;
            float v = 0.f;
            if (gr < M && gc < K) v = A[(size_t)gr * lda + gc];
            As[c][r] = v;
        }
#pragma unroll
        for (int i = 0; i < 8; i++) {
            int idx = tid + i * 256;
            int r = idx >> 4, c = idx & 15;
            int gr = bn + r, gc = k0 + c;
            float v = 0.f;
            if (gr < N && gc < K) v = B[(size_t)gr * ldb + gc];
            Bs[c][r] = v;
        }
        __syncthreads();
#pragma unroll
        for (int k = 0; k < BK; k++) {
            float a[8], bb[8];
#pragma unroll
            for (int i = 0; i < 8; i++) a[i] = As[k][ty * 8 + i];
#pragma unroll
            for (int j = 0; j < 8; j++) bb[j] = Bs[k][tx * 8 + j];
#pragma unroll
            for (int i = 0; i < 8; i++)
#pragma unroll
                for (int j = 0; j < 8; j++)
                    acc[i][j] = fmaf(a[i], bb[j], acc[i][j]);
        }
        __syncthreads();
    }
#pragma unroll
    for (int i = 0; i < 8; i++) {
        int gm = bm + ty * 8 + i;
        if (gm >= M) continue;
#pragma unroll
        for (int j = 0; j < 8; j++) {
            int gn = bn + tx * 8 + j;
            if (gn >= N) continue;
            float v = acc[i][j];
            if (EPI == 1) v = softplus_f(v + bias[gn]);
            if (EPI == 2) v += C[(size_t)gm * ldc + gn];
            C[(size_t)gm * ldc + gn] = v;
        }
    }
}

// ---------------- selective scan: one thread per channel d -------------------
// s[n] = exp(delta*A[d,n])*s[n] + delta*B[l,n]*u;  y[l,d] = sum_n s[n]*C[l,n] + u*Dp[d]
__global__ __launch_bounds__(256) void scan_k(
    const float* __restrict__ xc, const float* __restrict__ delta,
    const float* __restrict__ xdbl, const float* __restrict__ Alog,
    const float* __restrict__ Dpv, float* __restrict__ y) {
    int d = blockIdx.x * 256 + threadIdx.x;             // 0..DINNER-1
    float a[DSTATE];
    const float* Al = Alog + (size_t)d * DSTATE;
#pragma unroll
    for (int n = 0; n < DSTATE; n++) a[n] = -__expf(Al[n]);
    float s[DSTATE];
#pragma unroll
    for (int n = 0; n < DSTATE; n++) s[n] = 0.f;
    float Dd = Dpv[d];
    for (int l = 0; l < L_SEQ; l++) {
        float dlt = delta[(size_t)l * DINNER + d];
        float u = xc[(size_t)l * DINNER + d];
        const float* Brow = xdbl + (size_t)l * 96 + DTRANK;
        const float* Crow = Brow + DSTATE;
        float du = dlt * u;
        float accv = 0.f;
#pragma unroll
        for (int n = 0; n < DSTATE; n++) {
            float e = __expf(dlt * a[n]);
            s[n] = fmaf(e, s[n], du * Brow[n]);
            accv = fmaf(s[n], Crow[n], accv);
        }
        y[(size_t)l * DINNER + d] = fmaf(u, Dd, accv);
    }
}

extern "C" void kernel_launch(void* const* d_in, const int* in_sizes, int n_in,
                              void* d_out, int out_size, void* d_ws, size_t ws_size,
                              hipStream_t stream) {
    (void)in_sizes; (void)n_in; (void)out_size; (void)ws_size;
    const int*   tokens    = (const int*)d_in[0];
    const float* emb_W     = (const float*)d_in[1];
    const float* in_proj_W = (const float*)d_in[2];
    const float* conv_W    = (const float*)d_in[3];
    const float* conv_b    = (const float*)d_in[4];
    const float* xproj_W   = (const float*)d_in[5];
    const float* dt_W      = (const float*)d_in[6];
    const float* dt_b      = (const float*)d_in[7];
    const float* A_log     = (const float*)d_in[8];
    const float* Dp        = (const float*)d_in[9];
    const float* out_W     = (const float*)d_in[10];
    const float* rms_w     = (const float*)d_in[11];
    const float* rms_b     = (const float*)d_in[12];
    const float* normf_w   = (const float*)d_in[13];
    const float* normf_b   = (const float*)d_in[14];
    float* out = (float*)d_out;

    float* ws   = (float*)d_ws;
    float* x    = ws;                          // [L, 1024]
    float* h    = x    + (size_t)L_SEQ * NEMBD;        // [L, 1024]
    float* xr   = h    + (size_t)L_SEQ * NEMBD;        // [L, 4096]
    float* xc   = xr   + (size_t)L_SEQ * 2 * DINNER;   // [L, 2048]
    float* xdbl = xc   + (size_t)L_SEQ * DINNER;       // [L, 96]
    float* dlt  = xdbl + (size_t)L_SEQ * 96;           // [L, 2048]
    float* y    = dlt  + (size_t)L_SEQ * DINNER;       // [L, 2048]

    dim3 blk(256);

    // embedding
    embed_k<<<(L_SEQ * NEMBD) / 256, blk, 0, stream>>>(tokens, emb_W, x);

    for (int i = 0; i < NLAYERS; i++) {
        const float* ipW = in_proj_W + (size_t)i * 2 * DINNER * NEMBD;
        const float* cW  = conv_W   + (size_t)i * DINNER * DCONV;
        const float* cB  = conv_b   + (size_t)i * DINNER;
        const float* xpW = xproj_W  + (size_t)i * 96 * DINNER;
        const float* dW  = dt_W     + (size_t)i * DINNER * DTRANK;
        const float* dB  = dt_b     + (size_t)i * DINNER;
        const float* Al  = A_log    + (size_t)i * DINNER * DSTATE;
        const float* Dl  = Dp       + (size_t)i * DINNER;
        const float* oW  = out_W    + (size_t)i * NEMBD * DINNER;

        // h = rmsnorm(x)
        rmsnorm_k<<<L_SEQ, blk, 0, stream>>>(x, rms_w + (size_t)i * NEMBD,
                                             rms_b + (size_t)i * NEMBD, h);
        // xr = h @ in_proj^T  [L, 4096]
        {
            dim3 g((2 * DINNER + BN - 1) / BN, (L_SEQ + BM - 1) / BM);
            gemm_bt<0><<<g, blk, 0, stream>>>(h, NEMBD, ipW, NEMBD, xr, 2 * DINNER,
                                              nullptr, L_SEQ, 2 * DINNER, NEMBD);
        }
        // xc = silu(causal_conv(xr[:, :DINNER]) + conv_b)
        conv_silu_k<<<(L_SEQ * DINNER) / 256, blk, 0, stream>>>(xr, cW, cB, xc);
        // xdbl = xc @ xproj^T  [L, 96]
        {
            dim3 g((96 + BN - 1) / BN, (L_SEQ + BM - 1) / BM);
            gemm_bt<0><<<g, blk, 0, stream>>>(xc, DINNER, xpW, DINNER, xdbl, 96,
                                              nullptr, L_SEQ, 96, DINNER);
        }
        // delta = softplus(xdbl[:, :64] @ dt_W^T + dt_b)  [L, 2048]
        {
            dim3 g((DINNER + BN - 1) / BN, (L_SEQ + BM - 1) / BM);
            gemm_bt<1><<<g, blk, 0, stream>>>(xdbl, 96, dW, DTRANK, dlt, DINNER,
                                              dB, L_SEQ, DINNER, DTRANK);
        }
        // selective scan -> y
        scan_k<<<DINNER / 256, blk, 0, stream>>>(xc, dlt, xdbl, Al, Dl, y);
        // y *= silu(res)
        mul_silu_k<<<(L_SEQ * DINNER) / 256, blk, 0, stream>>>(y, xr);
        // x += y @ out_W^T
        {
            dim3 g((NEMBD + BN - 1) / BN, (L_SEQ + BM - 1) / BM);
            gemm_bt<2><<<g, blk, 0, stream>>>(y, DINNER, oW, DINNER, x, NEMBD,
                                              nullptr, L_SEQ, NEMBD, DINNER);
        }
    }

    // final norm + tied LM head
    rmsnorm_k<<<L_SEQ, blk, 0, stream>>>(x, normf_w, normf_b, h);
    {
        dim3 g((VOCAB + BN - 1) / BN, (L_SEQ + BM - 1) / BM);
        gemm_bt<0><<<g, blk, 0, stream>>>(h, NEMBD, emb_W, NEMBD, out, VOCAB,
                                          nullptr, L_SEQ, VOCAB, NEMBD);
    }
}